// Round 8
// baseline (16838.713 us; speedup 1.0000x reference)
//
#include <hip/hip_runtime.h>

static constexpr int B_ = 8;
static constexpr int C_ = 64;
static constexpr int H_ = 256;
static constexpr int W_ = 512;
static constexpr int K_ = 9;
static constexpr int PAD_ = 4;

// workspace layout (bytes)
static constexpr size_t FLAGS_OFF = 0;                 // 4 dirs x 256 blk x 128 B
static constexpr size_t FLAGS_PER_DIR = 256 * 128;     // 32 KB
static constexpr size_t XCC_OFF = 4 * FLAGS_PER_DIR;   // 128 KB
static constexpr size_t XCC_PER_DIR = 256 * 4;         // 1 KB
static constexpr size_t INIT_BYTES = XCC_OFF + 4 * XCC_PER_DIR;
static constexpr size_t HALO_OFF = 1ull << 20;         // 1 MB
static constexpr size_t HALO_PER_DIR = 1ull << 20;
static constexpr size_t TBUF_OFF = 16ull << 20;        // 16 MB

// ---------- agent(IC)-scope ops (cross-XCD safe) ----------
__device__ __forceinline__ float ic_load_f32(const float* p) {
    unsigned u = __hip_atomic_load((const unsigned*)p, __ATOMIC_RELAXED,
                                   __HIP_MEMORY_SCOPE_AGENT);
    return __uint_as_float(u);
}

// ---------- XCD-L2-scope ops (same-XCD links only; runtime-verified) -------
__device__ __forceinline__ unsigned xcc_id() {
    unsigned v;
    asm volatile("s_getreg_b32 %0, hwreg(HW_REG_XCC_ID)" : "=s"(v));
    return v & 0xffu;
}
__device__ __forceinline__ void l2_put_u64(void* p, unsigned long long v) {
    asm volatile("global_atomic_swap_x2 %0, %1, off" :: "v"(p), "v"(v)
                 : "memory");
}
__device__ __forceinline__ void l2_put_u32(void* p, unsigned v) {
    asm volatile("global_atomic_swap %0, %1, off" :: "v"(p), "v"(v)
                 : "memory");
}
__device__ __forceinline__ unsigned l2_get_u32(void* p) {
    unsigned v;
    asm volatile("global_atomic_add %0, %1, %2, off sc0\n\t"
                 "s_waitcnt vmcnt(0)"
                 : "=&v"(v) : "v"(p), "v"(0u) : "memory");
    return v;
}
__device__ __forceinline__ float l2_get_f32(void* p) {
    return __uint_as_float(l2_get_u32(p));
}
__device__ __forceinline__ unsigned long long pack2(float a, float b) {
    return (unsigned long long)__float_as_uint(a) |
           ((unsigned long long)__float_as_uint(b) << 32);
}

// Persistent directional scan, EDGE-FIRST schedule.
// Block = all 64 channels x T=16 cols. prev row double-buffered in LDS
// (28-float row stride -> conflict-free 4-row-group ds_read_b128).
// Per step: import halo -> compute 8 EDGE cols -> export+flag immediately
// -> compute 8 interior cols + RMW + stores. Only the edge conv sits on the
// inter-block chain. Mapping b=blk&7 (batch==XCD under round-robin),
// tile=blk>>3, neighbors +-8; link scope from measured XCC ids.
template <int T>
__global__ __launch_bounds__(256, 1) void scan_edge_kernel(
    float* __restrict__ buf, const float* __restrict__ w,
    const float* __restrict__ bias, const int N,
    const long long rowStride, const long long colStride,
    const long long chanStride, const int startRow, const int rowDir,
    const int numSteps, unsigned* __restrict__ flags,
    float* __restrict__ halo, unsigned* __restrict__ xccmap)
{
    static_assert(T == 16, "edge/interior split assumes T==16");
    constexpr int WIN = T + 8;    // 24 staged cols
    constexpr int STR = 28;       // LDS row stride (floats): banks {0,20,24,28}
    constexpr int NB = 8;         // neighbor stride in blockIdx
    __shared__ float prevb[2][C_][STR];
    __shared__ unsigned s_ic[2];

    const int tid = threadIdx.x;
    const int co = tid >> 2;
    const int g = tid & 3;
    const int TPB = N / T;
    const int blk = blockIdx.x;
    const int b = blk & 7;
    const int tile = blk >> 3;
    const int t0 = tile * T;
    const bool hasL = tile > 0;
    const bool hasR = tile < TPB - 1;

    // ---- one-time link-scope discovery ----
    bool icL = hasL, icR = hasR;
    if (flags != nullptr) {
        if (tid == 0) {
            const unsigned my = xcc_id();
            __hip_atomic_store(xccmap + blk, 0x100u | my, __ATOMIC_RELAXED,
                               __HIP_MEMORY_SCOPE_AGENT);
            unsigned xl = 0, xr = 0;
            if (hasL)
                while (!((xl = __hip_atomic_load(xccmap + blk - NB,
                                                 __ATOMIC_RELAXED,
                                                 __HIP_MEMORY_SCOPE_AGENT)) &
                         0x100u))
                    __builtin_amdgcn_s_sleep(1);
            if (hasR)
                while (!((xr = __hip_atomic_load(xccmap + blk + NB,
                                                 __ATOMIC_RELAXED,
                                                 __HIP_MEMORY_SCOPE_AGENT)) &
                         0x100u))
                    __builtin_amdgcn_s_sleep(1);
            s_ic[0] = (hasL && ((xl & 0xffu) != my)) ? 1u : 0u;
            s_ic[1] = (hasR && ((xr & 0xffu) != my)) ? 1u : 0u;
        }
        __syncthreads();
        icL = s_ic[0] != 0;
        icR = s_ic[1] != 0;
    }

    const long long base = (long long)b * C_ * chanStride;

    // weights w[co][ci=g+4i][k] -> 144 VGPRs, resident (bounds(256,1))
    float wreg[16][K_];
    {
        const float* wb_ = w + (long long)co * C_ * K_;
#pragma unroll
        for (int i = 0; i < 16; ++i)
#pragma unroll
            for (int k = 0; k < K_; ++k)
                wreg[i][k] = wb_[(g + 4 * i) * K_ + k];
    }
    const float bco = bias[co];

    for (int s = 0; s < numSteps; ++s) {
        const int irow = startRow + s * rowDir;
        float* rb = &prevb[s & 1][0][0];
        float* wbuf = &prevb[(s + 1) & 1][0][0];
        const long long orow = base + (long long)co * chanStride +
                               (long long)irow * rowStride;
        const int colL = t0 + g * 4;

        // RMW input prefetch — independent of neighbors, issue before waits
        float xv[4];
        if (colStride == 1) {
            const float4 v4 = *(const float4*)(buf + orow + colL);
            xv[0] = v4.x; xv[1] = v4.y; xv[2] = v4.z; xv[3] = v4.w;
        } else {
#pragma unroll
            for (int cc = 0; cc < 4; ++cc)
                xv[cc] = buf[orow + (long long)(colL + cc) * colStride];
        }

        if (s == 0) {
            // stage carry row (64 ci x 24 cols) + zero BOTH buffers' edge cols
            const long long pr = base + (long long)(irow - rowDir) * rowStride;
            for (int idx = tid; idx < C_ * WIN; idx += 256) {
                const int ci = idx / WIN, j = idx - ci * WIN;
                const int gc = t0 + j - PAD_;
                float v = 0.f;
                if (gc >= 0 && gc < N)
                    v = buf[pr + (long long)ci * chanStride +
                            (long long)gc * colStride];
                rb[ci * STR + j] = v;
            }
            for (int idx = tid; idx < C_ * 8; idx += 256) {
                const int ci = idx >> 3, j2 = idx & 7;
                wbuf[ci * STR + (j2 < 4 ? j2 : T + 4 + (j2 - 4))] = 0.f;
            }
        } else {
            // wait for neighbors' step s-1 (two waves spin in parallel)
            if (tid == 0 && hasL) {
                unsigned* fp = (unsigned*)((char*)flags + (blk - NB) * 128) +
                               (icL ? 16 : 0);
                if (icL) {
                    while (__hip_atomic_load(fp, __ATOMIC_RELAXED,
                                             __HIP_MEMORY_SCOPE_AGENT) <
                           (unsigned)s)
                        __builtin_amdgcn_s_sleep(1);
                } else {
                    while (l2_get_u32(fp) < (unsigned)s)
                        __builtin_amdgcn_s_sleep(1);
                }
            }
            if (tid == 64 && hasR) {
                unsigned* fp = (unsigned*)((char*)flags + (blk + NB) * 128) +
                               (icR ? 16 : 0);
                if (icR) {
                    while (__hip_atomic_load(fp, __ATOMIC_RELAXED,
                                             __HIP_MEMORY_SCOPE_AGENT) <
                           (unsigned)s)
                        __builtin_amdgcn_s_sleep(1);
                } else {
                    while (l2_get_u32(fp) < (unsigned)s)
                        __builtin_amdgcn_s_sleep(1);
                }
            }
            __syncthreads();
            // import halos (thread t -> ci=t>>2, c=t&3), parity (s-1)&1
            const int par = (s - 1) & 1;
            const int ci = tid >> 2, c = tid & 3;
            if (hasL) {
                float* p = halo + (((blk - NB) * 2 + par) * 2 + 1) * 256 + tid;
                rb[ci * STR + c] = icL ? ic_load_f32(p) : l2_get_f32(p);
            }
            if (hasR) {
                float* p = halo + (((blk + NB) * 2 + par) * 2 + 0) * 256 + tid;
                rb[ci * STR + T + 4 + c] = icR ? ic_load_f32(p) : l2_get_f32(p);
            }
        }
        __syncthreads();

        // ================= EDGE phase: cols 0-3 and 12-15 =================
        float accL[4] = {0.f, 0.f, 0.f, 0.f};
        float accR[4] = {0.f, 0.f, 0.f, 0.f};
#pragma unroll
        for (int i = 0; i < 16; ++i) {
            const float* rp = rb + (g + 4 * i) * STR;
            const float4 a0 = *(const float4*)(rp + 0);
            const float4 a1 = *(const float4*)(rp + 4);
            const float4 a2 = *(const float4*)(rp + 8);
            const float4 b0 = *(const float4*)(rp + 12);
            const float4 b1 = *(const float4*)(rp + 16);
            const float4 b2 = *(const float4*)(rp + 20);
            const float wl[12] = {a0.x, a0.y, a0.z, a0.w, a1.x, a1.y,
                                  a1.z, a1.w, a2.x, a2.y, a2.z, a2.w};
            const float wr2[12] = {b0.x, b0.y, b0.z, b0.w, b1.x, b1.y,
                                   b1.z, b1.w, b2.x, b2.y, b2.z, b2.w};
#pragma unroll
            for (int k = 0; k < K_; ++k) {
                const float wk = wreg[i][k];
#pragma unroll
                for (int c = 0; c < 4; ++c) {
                    accL[c] = fmaf(wk, wl[c + k], accL[c]);
                    accR[c] = fmaf(wk, wr2[c + k], accR[c]);
                }
            }
        }
#pragma unroll
        for (int c = 0; c < 4; ++c) {
            accL[c] += __shfl_xor(accL[c], 1);
            accR[c] += __shfl_xor(accR[c], 1);
        }
#pragma unroll
        for (int c = 0; c < 4; ++c) {
            accL[c] += __shfl_xor(accL[c], 2);
            accR[c] += __shfl_xor(accR[c], 2);
        }

        float r[4];
        if (g == 0) {
#pragma unroll
            for (int c = 0; c < 4; ++c) {
                r[c] = xv[c] + fmaxf(accL[c] + bco, 0.f);
                wbuf[co * STR + 4 + c] = r[c];
            }
            if (hasL && flags != nullptr && s != numSteps - 1) {
                float* p = halo + ((blk * 2 + (s & 1)) * 2 + 0) * 256 + co * 4;
                const unsigned long long p0 = pack2(r[0], r[1]);
                const unsigned long long p1 = pack2(r[2], r[3]);
                if (icL) {
                    (void)__hip_atomic_exchange((unsigned long long*)p, p0,
                                                __ATOMIC_RELAXED,
                                                __HIP_MEMORY_SCOPE_AGENT);
                    (void)__hip_atomic_exchange((unsigned long long*)(p + 2),
                                                p1, __ATOMIC_RELAXED,
                                                __HIP_MEMORY_SCOPE_AGENT);
                } else {
                    l2_put_u64(p, p0);
                    l2_put_u64(p + 2, p1);
                }
            }
        } else if (g == 3) {
#pragma unroll
            for (int c = 0; c < 4; ++c) {
                r[c] = xv[c] + fmaxf(accR[c] + bco, 0.f);
                wbuf[co * STR + 4 + 12 + c] = r[c];
            }
            if (hasR && flags != nullptr && s != numSteps - 1) {
                float* p = halo + ((blk * 2 + (s & 1)) * 2 + 1) * 256 + co * 4;
                const unsigned long long p0 = pack2(r[0], r[1]);
                const unsigned long long p1 = pack2(r[2], r[3]);
                if (icR) {
                    (void)__hip_atomic_exchange((unsigned long long*)p, p0,
                                                __ATOMIC_RELAXED,
                                                __HIP_MEMORY_SCOPE_AGENT);
                    (void)__hip_atomic_exchange((unsigned long long*)(p + 2),
                                                p1, __ATOMIC_RELAXED,
                                                __HIP_MEMORY_SCOPE_AGENT);
                } else {
                    l2_put_u64(p, p0);
                    l2_put_u64(p + 2, p1);
                }
            }
        }

        // publish flag as soon as edge exports are drained
        if (flags != nullptr && s != numSteps - 1) {
            asm volatile("s_waitcnt vmcnt(0)" ::: "memory");
            __syncthreads();
            if (tid == 0) {
                const unsigned val = (unsigned)(s + 1);
                unsigned* fb = (unsigned*)((char*)flags + blk * 128);
                if ((hasL && !icL) || (hasR && !icR)) l2_put_u32(fb, val);
                if ((hasL && icL) || (hasR && icR))
                    __hip_atomic_store(fb + 16, val, __ATOMIC_RELAXED,
                                       __HIP_MEMORY_SCOPE_AGENT);
            }
        }

        // ================= INTERIOR phase: cols 4-11 =================
        float accI[8] = {0.f, 0.f, 0.f, 0.f, 0.f, 0.f, 0.f, 0.f};
#pragma unroll
        for (int i = 0; i < 16; ++i) {
            const float* rp = rb + (g + 4 * i) * STR;
            const float4 c0 = *(const float4*)(rp + 4);
            const float4 c1 = *(const float4*)(rp + 8);
            const float4 c2 = *(const float4*)(rp + 12);
            const float4 c3 = *(const float4*)(rp + 16);
            const float wm[16] = {c0.x, c0.y, c0.z, c0.w, c1.x, c1.y, c1.z,
                                  c1.w, c2.x, c2.y, c2.z, c2.w, c3.x, c3.y,
                                  c3.z, c3.w};
#pragma unroll
            for (int k = 0; k < K_; ++k) {
                const float wk = wreg[i][k];
#pragma unroll
                for (int c = 0; c < 8; ++c)
                    accI[c] = fmaf(wk, wm[c + k], accI[c]);
            }
        }
#pragma unroll
        for (int c = 0; c < 8; ++c) accI[c] += __shfl_xor(accI[c], 1);
#pragma unroll
        for (int c = 0; c < 8; ++c) accI[c] += __shfl_xor(accI[c], 2);

        if (g == 1 || g == 2) {
            const int o = (g - 1) * 4;
#pragma unroll
            for (int c = 0; c < 4; ++c) {
                r[c] = xv[c] + fmaxf(accI[o + c] + bco, 0.f);
                wbuf[co * STR + 8 + o + c] = r[c];
            }
        }

        // store output row (all threads)
        if (colStride == 1) {
            const float4 v4 = {r[0], r[1], r[2], r[3]};
            *(float4*)(buf + orow + colL) = v4;
        } else {
#pragma unroll
            for (int cc = 0; cc < 4; ++cc)
                buf[orow + (long long)(colL + cc) * colStride] = r[cc];
        }

        __syncthreads();  // wbuf complete before next step reads it
    }
}

// out[b,c,s,r] = in[b,c,r,s] for each of the B*C planes.
__global__ __launch_bounds__(256) void transpose_kernel(
    const float* __restrict__ in, float* __restrict__ out,
    const int R, const int S)
{
    __shared__ float tile[32][33];
    const size_t plane = (size_t)blockIdx.z * R * S;
    const int s0 = blockIdx.x * 32;
    const int r0 = blockIdx.y * 32;
    const int tx = threadIdx.x;
    const int ty = threadIdx.y;
#pragma unroll
    for (int j = 0; j < 32; j += 8)
        tile[ty + j][tx] = in[plane + (size_t)(r0 + ty + j) * S + s0 + tx];
    __syncthreads();
#pragma unroll
    for (int j = 0; j < 32; j += 8)
        out[plane + (size_t)(s0 + ty + j) * R + r0 + tx] = tile[tx][ty + j];
}

static void launch_dir(float* buf, const float* w, const float* bias, int N,
                       long long rowStride, long long colStride,
                       long long chanStride, int startRow, int rowDir,
                       int numSteps, unsigned* flags, float* halo,
                       unsigned* xccmap, bool persistent, hipStream_t stream)
{
    const int nblocks = 8 * (N / 16);
    if (persistent) {
        scan_edge_kernel<16><<<nblocks, 256, 0, stream>>>(
            buf, w, bias, N, rowStride, colStride, chanStride, startRow,
            rowDir, numSteps, flags, halo, xccmap);
    } else {
        for (int s = 0; s < numSteps; ++s)
            scan_edge_kernel<16><<<nblocks, 256, 0, stream>>>(
                buf, w, bias, N, rowStride, colStride, chanStride,
                startRow + s * rowDir, rowDir, 1, nullptr, nullptr, nullptr);
    }
}

extern "C" void kernel_launch(void* const* d_in, const int* in_sizes, int n_in,
                              void* d_out, int out_size, void* d_ws,
                              size_t ws_size, hipStream_t stream)
{
    const float* x    = (const float*)d_in[0];
    const float* w_ud = (const float*)d_in[1];
    const float* b_ud = (const float*)d_in[2];
    const float* w_du = (const float*)d_in[3];
    const float* b_du = (const float*)d_in[4];
    const float* w_lr = (const float*)d_in[5];
    const float* b_lr = (const float*)d_in[6];
    const float* w_rl = (const float*)d_in[7];
    const float* b_rl = (const float*)d_in[8];
    float* out = (float*)d_out;

    const size_t total = (size_t)B_ * C_ * H_ * W_;
    const long long chan = (long long)H_ * W_;

    const bool haveSync = ws_size >= HALO_OFF + 4 * HALO_PER_DIR;
    const bool haveT = ws_size >= TBUF_OFF + total * sizeof(float);

    float* wsT = (float*)((char*)d_ws + TBUF_OFF);

    hipMemcpyAsync(out, x, total * sizeof(float), hipMemcpyDeviceToDevice,
                   stream);
    if (haveSync) hipMemsetAsync(d_ws, 0, INIT_BYTES, stream);

    unsigned* fl[4];
    float* hl[4];
    unsigned* xm[4];
    for (int d = 0; d < 4; ++d) {
        fl[d] = (unsigned*)((char*)d_ws + FLAGS_OFF + d * FLAGS_PER_DIR);
        hl[d] = (float*)((char*)d_ws + HALO_OFF + d * HALO_PER_DIR);
        xm[d] = (unsigned*)((char*)d_ws + XCC_OFF + d * XCC_PER_DIR);
    }

    // up->down / down->up on [b,c,h,w]: scan h, conv along w (contig, N=512)
    launch_dir(out, w_ud, b_ud, W_, (long long)W_, 1LL, chan,
               1, +1, H_ - 1, fl[0], hl[0], xm[0], haveSync, stream);
    launch_dir(out, w_du, b_du, W_, (long long)W_, 1LL, chan,
               H_ - 2, -1, H_ - 1, fl[1], hl[1], xm[1], haveSync, stream);

    if (haveT) {
        // transpose to [b,c,w,h]: scan w, conv along h (contig, N=256)
        {
            dim3 gt(W_ / 32, H_ / 32, B_ * C_);
            transpose_kernel<<<gt, dim3(32, 8), 0, stream>>>(out, wsT, H_, W_);
        }
        launch_dir(wsT, w_lr, b_lr, H_, (long long)H_, 1LL, chan,
                   1, +1, W_ - 1, fl[2], hl[2], xm[2], haveSync, stream);
        launch_dir(wsT, w_rl, b_rl, H_, (long long)H_, 1LL, chan,
                   W_ - 2, -1, W_ - 1, fl[3], hl[3], xm[3], haveSync, stream);
        {
            dim3 gt(H_ / 32, W_ / 32, B_ * C_);
            transpose_kernel<<<gt, dim3(32, 8), 0, stream>>>(wsT, out, W_, H_);
        }
    } else {
        // strided fallback on [b,c,h,w]: scan w (rowStride=1), conv along h
        launch_dir(out, w_lr, b_lr, H_, 1LL, (long long)W_, chan,
                   1, +1, W_ - 1, fl[2], hl[2], xm[2], haveSync, stream);
        launch_dir(out, w_rl, b_rl, H_, 1LL, (long long)W_, chan,
                   W_ - 2, -1, W_ - 1, fl[3], hl[3], xm[3], haveSync, stream);
    }
}

// Round 11
// 10485.908 us; speedup vs baseline: 1.6058x; 1.6058x over previous
//
#include <hip/hip_runtime.h>

static constexpr int B_ = 8;
static constexpr int C_ = 64;
static constexpr int H_ = 256;
static constexpr int W_ = 512;
static constexpr int K_ = 9;
static constexpr int PAD_ = 4;

typedef unsigned long long u64;

// workspace layout (bytes)
static constexpr size_t XCC_OFF = 0;                   // 4 dirs x 256 x 4 B
static constexpr size_t XCC_PER_DIR = 256 * 4;
static constexpr size_t HALO_OFF = 1ull << 20;         // 1 MB
static constexpr size_t HALO_PER_DIR = 2ull << 20;     // 256blk*2par*2side*256*8B
static constexpr size_t INIT_BYTES = HALO_OFF + 4 * HALO_PER_DIR;  // 9 MB
static constexpr size_t TBUF_OFF = 16ull << 20;        // 16 MB

// ---------- halo sync primitives ----------
// LESSON (rounds 9+10 both deadlocked): consumer polls MUST be inline-asm
// atomic RMWs. A plain load (r9, `sc0`) or a compiler-optimizable
// fetch_add(0) at workgroup scope (r10) gets served from the non-coherent
// per-CU L1 forever -> infinite spin. Inline-asm global_atomic_* always
// executes at the L2/IC and cannot be demoted by the compiler.
//   same-XCD link  -> global_atomic_{swap,add}_x2 (no sc1): issuing XCD's L2.
//   cross-XCD link -> agent-scope intrinsics (via IC), proven rounds 6-8.
__device__ __forceinline__ void l2_put_u64(u64* p, u64 v) {
    asm volatile("global_atomic_swap_x2 %0, %1, off" :: "v"(p), "v"(v)
                 : "memory");
}
__device__ __forceinline__ u64 l2_get_u64(const u64* p) {
    u64 v;
    asm volatile("global_atomic_add_x2 %0, %1, %2, off sc0\n\t"
                 "s_waitcnt vmcnt(0)"
                 : "=&v"(v) : "v"(p), "v"(0ull) : "memory");
    return v;
}
__device__ __forceinline__ u64 ic_get_u64(const u64* p) {
    return __hip_atomic_load(p, __ATOMIC_RELAXED, __HIP_MEMORY_SCOPE_AGENT);
}
__device__ __forceinline__ void ic_put_u64(u64* p, u64 v) {
    (void)__hip_atomic_exchange(p, v, __ATOMIC_RELAXED,
                                __HIP_MEMORY_SCOPE_AGENT);
}
__device__ __forceinline__ u64 halo_read(const u64* p, bool ic) {
    return ic ? ic_get_u64(p) : l2_get_u64(p);
}
__device__ __forceinline__ void halo_write(u64* p, u64 v, bool ic) {
    if (ic) ic_put_u64(p, v);
    else    l2_put_u64(p, v);
}
__device__ __forceinline__ u64 pack_tag(float val, unsigned tag) {
    return (u64)__float_as_uint(val) | ((u64)tag << 32);
}
__device__ __forceinline__ unsigned xcc_id() {
    unsigned v;
    asm volatile("s_getreg_b32 %0, hwreg(HW_REG_XCC_ID)" : "=s"(v));
    return v & 0xffu;
}

// Persistent directional scan with tagged single-hop halo exchange.
// Block = all 64 channels x T cols of one batch. Carry row lives in LDS
// across steps (STR=WIN+4 padding -> the 4 rows of one ds_read group land on
// distinct banks). Thread t: co=t>>2, g=t&3 (ci-quarter). Per step:
// xv prefetch -> poll+import tagged halos (tag+value in ONE 8B atomic) ->
// sync -> conv (16ci x 9k x T) -> butterfly over g -> export tagged edges +
// store -> sync -> own cols to LDS. Mapping b=blk&7 (batch==XCD under
// round-robin dispatch), tile=blk>>3, neighbors +-8; per-link scope from
// measured XCC ids (correct even if the dispatch-mapping assumption breaks).
// Slot-reuse safety (parity slots, period 2): A's step-(s+2) clobber of a
// slot requires A's step-(s+1)..(s+2) imports, which require B's step-(s+1)
// export, which happens only after B's step-(s+1) import consumed A's
// step-s tag. So a tag is never overwritten before its consumer reads it.
template <int T>
__global__ __launch_bounds__(256, 1) void scan_tag_kernel(
    float* __restrict__ buf, const float* __restrict__ w,
    const float* __restrict__ bias, const int N,
    const long long rowStride, const long long colStride,
    const long long chanStride, const int startRow, const int rowDir,
    const int numSteps, u64* __restrict__ halo,
    unsigned* __restrict__ xccmap)
{
    constexpr int CPT = T / 4;    // cols per thread (4 or 2)
    constexpr int WIN = T + 8;    // staged window per ci
    constexpr int STR = WIN + 4;  // LDS row stride: conflict-free bank groups
    constexpr int NB = 8;         // neighbor stride in blockIdx
    __shared__ float prev[C_][STR];
    __shared__ unsigned s_ic[2];

    const int tid = threadIdx.x;
    const int co = tid >> 2;
    const int g = tid & 3;
    const int blk = blockIdx.x;
    const int b = blk & 7;
    const int tile = blk >> 3;
    const int TPB = N / T;
    const int t0 = tile * T;
    const bool hasL = tile > 0;
    const bool hasR = tile < TPB - 1;
    float* rb = &prev[0][0];

    // ---- one-time link-scope discovery ----
    bool icL = hasL, icR = hasR;
    if (halo != nullptr) {
        if (tid == 0) {
            const unsigned my = xcc_id();
            __hip_atomic_store(xccmap + blk, 0x100u | my, __ATOMIC_RELAXED,
                               __HIP_MEMORY_SCOPE_AGENT);
            unsigned xl = 0, xr = 0;
            if (hasL)
                while (!((xl = __hip_atomic_load(xccmap + blk - NB,
                                                 __ATOMIC_RELAXED,
                                                 __HIP_MEMORY_SCOPE_AGENT)) &
                         0x100u))
                    __builtin_amdgcn_s_sleep(1);
            if (hasR)
                while (!((xr = __hip_atomic_load(xccmap + blk + NB,
                                                 __ATOMIC_RELAXED,
                                                 __HIP_MEMORY_SCOPE_AGENT)) &
                         0x100u))
                    __builtin_amdgcn_s_sleep(1);
            s_ic[0] = (hasL && ((xl & 0xffu) != my)) ? 1u : 0u;
            s_ic[1] = (hasR && ((xr & 0xffu) != my)) ? 1u : 0u;
        }
        __syncthreads();
        icL = s_ic[0] != 0;
        icR = s_ic[1] != 0;
    }

    const long long base = (long long)b * C_ * chanStride;

    // weights w[co][ci=g+4i][k] -> 144 VGPRs, resident (bounds(256,1))
    float wreg[16][K_];
    {
        const float* wb_ = w + (long long)co * C_ * K_;
#pragma unroll
        for (int i = 0; i < 16; ++i)
#pragma unroll
            for (int k = 0; k < K_; ++k)
                wreg[i][k] = wb_[(g + 4 * i) * K_ + k];
    }
    const float bco = bias[co];

    for (int s = 0; s < numSteps; ++s) {
        const int irow = startRow + s * rowDir;
        const long long orowc = base + (long long)co * chanStride +
                                (long long)irow * rowStride;
        const int colL = t0 + g * CPT;

        // RMW input prefetch — independent of neighbors, issue before polls
        float xv[CPT];
        if (colStride == 1) {
            if constexpr (CPT == 4) {
                const float4 v4 = *(const float4*)(buf + orowc + colL);
                xv[0] = v4.x; xv[1] = v4.y; xv[2] = v4.z; xv[3] = v4.w;
            } else {
                const float2 v2 = *(const float2*)(buf + orowc + colL);
                xv[0] = v2.x; xv[1] = v2.y;
            }
        } else {
#pragma unroll
            for (int cc = 0; cc < CPT; ++cc)
                xv[cc] = buf[orowc + (long long)(colL + cc) * colStride];
        }

        if (s == 0) {
            // stage full carry-row window from global (prev direction output)
            const long long pr = base + (long long)(irow - rowDir) * rowStride;
            for (int idx = tid; idx < C_ * WIN; idx += 256) {
                const int ci = idx / WIN, j = idx - ci * WIN;
                const int gc = t0 + j - PAD_;
                float v = 0.f;
                if (gc >= 0 && gc < N)
                    v = buf[pr + (long long)ci * chanStride +
                            (long long)gc * colStride];
                rb[ci * STR + j] = v;
            }
        } else {
            // tagged import: poll OWN slot until tag==s. Issue left+right
            // reads back-to-back so the two round trips overlap.
            const int par = (s - 1) & 1;
            const unsigned want = (unsigned)s;
            const int ci = tid >> 2, c = tid & 3;
            const u64* pl =
                halo + (size_t)(((blk - NB) * 2 + par) * 2 + 1) * 256 + tid;
            const u64* pr2 =
                halo + (size_t)(((blk + NB) * 2 + par) * 2 + 0) * 256 + tid;
            u64 vl = 0, vr = 0;
            if (hasL) vl = halo_read(pl, icL);
            if (hasR) vr = halo_read(pr2, icR);
            while (true) {
                const bool okL = !hasL || (unsigned)(vl >> 32) == want;
                const bool okR = !hasR || (unsigned)(vr >> 32) == want;
                if (okL && okR) break;
                __builtin_amdgcn_s_sleep(1);
                if (!okL) vl = halo_read(pl, icL);
                if (!okR) vr = halo_read(pr2, icR);
            }
            if (hasL) rb[ci * STR + c] = __uint_as_float((unsigned)vl);
            if (hasR) rb[ci * STR + T + 4 + c] = __uint_as_float((unsigned)vr);
        }
        __syncthreads();  // SYNC_A: halos + interior updates visible

        // ---- conv: partial sums over my ci-quarter, all T cols ----
        float acc[T];
#pragma unroll
        for (int c = 0; c < T; ++c) acc[c] = 0.f;
#pragma unroll
        for (int i = 0; i < 16; ++i) {
            const float* rp = rb + (g + 4 * i) * STR;
            float win[WIN];
#pragma unroll
            for (int j = 0; j < WIN / 4; ++j) {
                const float4 v = *(const float4*)(rp + 4 * j);
                win[4 * j + 0] = v.x; win[4 * j + 1] = v.y;
                win[4 * j + 2] = v.z; win[4 * j + 3] = v.w;
            }
#pragma unroll
            for (int k = 0; k < K_; ++k) {
                const float wk = wreg[i][k];
#pragma unroll
                for (int c = 0; c < T; ++c)
                    acc[c] = fmaf(wk, win[c + k], acc[c]);
            }
        }
        // butterfly over g (lane bits 0-1): full sums in all 4 siblings
#pragma unroll
        for (int c = 0; c < T; ++c) acc[c] += __shfl_xor(acc[c], 1);
#pragma unroll
        for (int c = 0; c < T; ++c) acc[c] += __shfl_xor(acc[c], 2);

        float r[CPT];
#pragma unroll
        for (int cc = 0; cc < CPT; ++cc)
            r[cc] = xv[cc] + fmaxf(acc[g * CPT + cc] + bco, 0.f);

        // ---- export tagged edges ASAP (value+tag in one 8B atomic) ----
        if (s != numSteps - 1 && halo != nullptr) {
            const unsigned tag = (unsigned)(s + 1);
            const int par = s & 1;
            if constexpr (CPT == 2) {
                const int side = g >> 1;           // g0,g1 left; g2,g3 right
                const bool has = side ? hasR : hasL;
                if (has) {
                    const bool ic = side ? icR : icL;
                    u64* p = halo + (size_t)((blk * 2 + par) * 2 + side) * 256 +
                             co * 4 + (g & 1) * 2;
                    halo_write(p, pack_tag(r[0], tag), ic);
                    halo_write(p + 1, pack_tag(r[1], tag), ic);
                }
            } else {  // CPT==4: g0 owns full left edge, g3 full right edge
                if ((g == 0 && hasL) || (g == 3 && hasR)) {
                    const int side = (g == 0) ? 0 : 1;
                    const bool ic = (g == 0) ? icL : icR;
                    u64* p = halo + (size_t)((blk * 2 + par) * 2 + side) * 256 +
                             co * 4;
#pragma unroll
                    for (int cc = 0; cc < 4; ++cc)
                        halo_write(p + cc, pack_tag(r[cc], tag), ic);
                }
            }
        }

        // store output row (register-only operands; before SYNC_B)
        if (colStride == 1) {
            if constexpr (CPT == 4) {
                const float4 v4 = {r[0], r[1], r[2], r[3]};
                *(float4*)(buf + orowc + colL) = v4;
            } else {
                const float2 v2 = {r[0], r[1]};
                *(float2*)(buf + orowc + colL) = v2;
            }
        } else {
#pragma unroll
            for (int cc = 0; cc < CPT; ++cc)
                buf[orowc + (long long)(colL + cc) * colStride] = r[cc];
        }

        __syncthreads();  // SYNC_B: all conv reads of rb done
        // own outputs become next step's carry (interior slots only; next
        // import writes halo slots — disjoint, so no extra sync needed)
#pragma unroll
        for (int cc = 0; cc < CPT; ++cc)
            rb[co * STR + 4 + g * CPT + cc] = r[cc];
    }
}

// out[b,c,s,r] = in[b,c,r,s] for each of the B*C planes.
__global__ __launch_bounds__(256) void transpose_kernel(
    const float* __restrict__ in, float* __restrict__ out,
    const int R, const int S)
{
    __shared__ float tile[32][33];
    const size_t plane = (size_t)blockIdx.z * R * S;
    const int s0 = blockIdx.x * 32;
    const int r0 = blockIdx.y * 32;
    const int tx = threadIdx.x;
    const int ty = threadIdx.y;
#pragma unroll
    for (int j = 0; j < 32; j += 8)
        tile[ty + j][tx] = in[plane + (size_t)(r0 + ty + j) * S + s0 + tx];
    __syncthreads();
#pragma unroll
    for (int j = 0; j < 32; j += 8)
        out[plane + (size_t)(s0 + ty + j) * R + r0 + tx] = tile[tx][ty + j];
}

template <int T>
static void launch_dir(float* buf, const float* w, const float* bias, int N,
                       long long rowStride, long long colStride,
                       long long chanStride, int startRow, int rowDir,
                       int numSteps, u64* halo, unsigned* xccmap,
                       bool persistent, hipStream_t stream)
{
    const int nblocks = 8 * (N / T);   // 256 for both variants
    if (persistent) {
        scan_tag_kernel<T><<<nblocks, 256, 0, stream>>>(
            buf, w, bias, N, rowStride, colStride, chanStride, startRow,
            rowDir, numSteps, halo, xccmap);
    } else {
        for (int s = 0; s < numSteps; ++s)
            scan_tag_kernel<T><<<nblocks, 256, 0, stream>>>(
                buf, w, bias, N, rowStride, colStride, chanStride,
                startRow + s * rowDir, rowDir, 1, nullptr, nullptr);
    }
}

extern "C" void kernel_launch(void* const* d_in, const int* in_sizes, int n_in,
                              void* d_out, int out_size, void* d_ws,
                              size_t ws_size, hipStream_t stream)
{
    const float* x    = (const float*)d_in[0];
    const float* w_ud = (const float*)d_in[1];
    const float* b_ud = (const float*)d_in[2];
    const float* w_du = (const float*)d_in[3];
    const float* b_du = (const float*)d_in[4];
    const float* w_lr = (const float*)d_in[5];
    const float* b_lr = (const float*)d_in[6];
    const float* w_rl = (const float*)d_in[7];
    const float* b_rl = (const float*)d_in[8];
    float* out = (float*)d_out;

    const size_t total = (size_t)B_ * C_ * H_ * W_;
    const long long chan = (long long)H_ * W_;

    const bool haveSync = ws_size >= INIT_BYTES;
    const bool haveT = ws_size >= TBUF_OFF + total * sizeof(float);

    float* wsT = (float*)((char*)d_ws + TBUF_OFF);

    hipMemcpyAsync(out, x, total * sizeof(float), hipMemcpyDeviceToDevice,
                   stream);
    // zero xcc map + ALL tagged halos (kills stale tags across graph replays)
    if (haveSync) hipMemsetAsync(d_ws, 0, INIT_BYTES, stream);

    u64* hl[4];
    unsigned* xm[4];
    for (int d = 0; d < 4; ++d) {
        hl[d] = (u64*)((char*)d_ws + HALO_OFF + d * HALO_PER_DIR);
        xm[d] = (unsigned*)((char*)d_ws + XCC_OFF + d * XCC_PER_DIR);
    }

    // up->down / down->up on [b,c,h,w]: scan h, conv along w (contig, N=512)
    launch_dir<16>(out, w_ud, b_ud, W_, (long long)W_, 1LL, chan,
                   1, +1, H_ - 1, hl[0], xm[0], haveSync, stream);
    launch_dir<16>(out, w_du, b_du, W_, (long long)W_, 1LL, chan,
                   H_ - 2, -1, H_ - 1, hl[1], xm[1], haveSync, stream);

    if (haveT) {
        // transpose to [b,c,w,h]: scan w, conv along h (contig, N=256)
        {
            dim3 gt(W_ / 32, H_ / 32, B_ * C_);
            transpose_kernel<<<gt, dim3(32, 8), 0, stream>>>(out, wsT, H_, W_);
        }
        launch_dir<8>(wsT, w_lr, b_lr, H_, (long long)H_, 1LL, chan,
                      1, +1, W_ - 1, hl[2], xm[2], haveSync, stream);
        launch_dir<8>(wsT, w_rl, b_rl, H_, (long long)H_, 1LL, chan,
                      W_ - 2, -1, W_ - 1, hl[3], xm[3], haveSync, stream);
        {
            dim3 gt(H_ / 32, W_ / 32, B_ * C_);
            transpose_kernel<<<gt, dim3(32, 8), 0, stream>>>(wsT, out, W_, H_);
        }
    } else {
        // strided fallback on [b,c,h,w]: scan w (rowStride=1), conv along h
        launch_dir<8>(out, w_lr, b_lr, H_, 1LL, (long long)W_, chan,
                      1, +1, W_ - 1, hl[2], xm[2], haveSync, stream);
        launch_dir<8>(out, w_rl, b_rl, H_, 1LL, (long long)W_, chan,
                      W_ - 2, -1, W_ - 1, hl[3], xm[3], haveSync, stream);
    }
}

// Round 13
// 9101.662 us; speedup vs baseline: 1.8501x; 1.1521x over previous
//
#include <hip/hip_runtime.h>

static constexpr int B_ = 8;
static constexpr int C_ = 64;
static constexpr int H_ = 256;
static constexpr int W_ = 512;
static constexpr int K_ = 9;
static constexpr int PAD_ = 4;

typedef unsigned long long u64;

// workspace layout (bytes)
static constexpr size_t XCC_OFF = 0;                    // 4 dirs x 256 x 4 B
static constexpr size_t XCC_PER_DIR = 256 * 4;
static constexpr size_t TAG_OFF = 64ull << 10;          // 64 KB
static constexpr size_t TAG_PER_DIR = 128ull << 10;     // 256*2*2 slots x 64 B
static constexpr size_t HALO_A_OFF = 1ull << 20;        // 1 MB (IC tagged u64)
static constexpr size_t HALO_A_PER_DIR = 2ull << 20;    // 256*2*2*256*8 B
static constexpr size_t INIT_BYTES = HALO_A_OFF + 4 * HALO_A_PER_DIR;  // 9 MB
static constexpr size_t HALO_P_OFF = 9ull << 20;        // 9 MB (packed pairs)
static constexpr size_t HALO_P_PER_DIR = 1ull << 20;    // 256*2*2*128*8 B
static constexpr size_t TBUF_OFF = 16ull << 20;         // 16 MB

// ---------- sync primitives ----------
// PROVEN RULES (r6-r12): cross-block data/flag traffic must be atomic RMWs
// end-to-end. Plain loads (r9), relaxed wg-scope fetch_add (r10), and
// plain-store+inv schemes (r12) all broke on the non-coherent L1 or
// store/atomic ordering. r11 (all-atomic, tag-in-data) is correct but
// atomic-throughput-bound; this round keeps the atomic path and halves its
// cost: 2 floats per x2 swap + ONE central tag per side (published after a
// __syncthreads, whose compiler-emitted vmcnt(0) drains the data swaps to
// L2 first -> atomic->atomic same-L2 ordering, no plain-store trust).
__device__ __forceinline__ void l2_put_u64(u64* p, u64 v) {
    asm volatile("global_atomic_swap_x2 %0, %1, off" :: "v"(p), "v"(v)
                 : "memory");
}
__device__ __forceinline__ u64 l2_get_u64(const u64* p) {
    u64 v;
    asm volatile("global_atomic_add_x2 %0, %1, %2, off sc0\n\t"
                 "s_waitcnt vmcnt(0)"
                 : "=&v"(v) : "v"(p), "v"(0ull) : "memory");
    return v;
}
__device__ __forceinline__ u64 ic_get_u64(const u64* p) {
    return __hip_atomic_load(p, __ATOMIC_RELAXED, __HIP_MEMORY_SCOPE_AGENT);
}
__device__ __forceinline__ void ic_put_u64(u64* p, u64 v) {
    (void)__hip_atomic_exchange(p, v, __ATOMIC_RELAXED,
                                __HIP_MEMORY_SCOPE_AGENT);
}
__device__ __forceinline__ u64 pack_tag(float val, unsigned tag) {
    return (u64)__float_as_uint(val) | ((u64)tag << 32);
}
__device__ __forceinline__ u64 pack2f(float a, float b) {
    return (u64)__float_as_uint(a) | ((u64)__float_as_uint(b) << 32);
}
__device__ __forceinline__ unsigned xcc_id() {
    unsigned v;
    asm volatile("s_getreg_b32 %0, hwreg(HW_REG_XCC_ID)" : "=s"(v));
    return v & 0xffu;
}

// Persistent directional scan; packed-pair atomics + central per-side tags.
// Block = all 64 channels x T cols of one batch; carry row lives in LDS
// across steps (STR=WIN+4 bank padding). Thread t: co=t>>2, g=t&3.
// Per step: xv prefetch -> import (waves 0,1 left / 2,3 right: lane0 polls
// tag RMW, wave reconverges, each lane ONE data RMW -> rb halo) -> SYNC_A ->
// conv 16ci x 9k x T -> butterfly over g -> export pair-swaps -> SYNC_B
// (drains exports to L2) -> tag publish -> output stores -> rb interior.
// Mapping b=blk&7 (batch==XCD under round-robin), tile=blk>>3, neighbors
// +-8; per-link scope from measured XCC ids; cross-XCD links use r11's
// per-thread tag-in-data agent atomics (proven).
// Slot-reuse safety (parity 2): producer's step-(s+2) overwrite is gated on
// consumer's step-(s+1) tag, published after the consumer's step-s import
// read the slot. Same argument covers the tag slots themselves.
template <int T>
__global__ __launch_bounds__(256, 1) void scan_pair_kernel(
    float* __restrict__ buf, const float* __restrict__ w,
    const float* __restrict__ bias, const int N,
    const long long rowStride, const long long colStride,
    const long long chanStride, const int startRow, const int rowDir,
    const int numSteps, u64* __restrict__ halo_a, u64* __restrict__ halo_p,
    u64* __restrict__ tags, unsigned* __restrict__ xccmap)
{
    constexpr int CPT = T / 4;    // cols per thread (4 or 2)
    constexpr int WIN = T + 8;    // staged window per ci
    constexpr int STR = WIN + 4;  // LDS row stride: conflict-free bank groups
    constexpr int NB = 8;         // neighbor stride in blockIdx
    __shared__ float prev[C_][STR];
    __shared__ unsigned s_ic[2];

    const int tid = threadIdx.x;
    const int co = tid >> 2;
    const int g = tid & 3;
    const int blk = blockIdx.x;
    const int b = blk & 7;
    const int tile = blk >> 3;
    const int TPB = N / T;
    const int t0 = tile * T;
    const bool hasL = tile > 0;
    const bool hasR = tile < TPB - 1;
    float* rb = &prev[0][0];

    // ---- one-time link-scope discovery ----
    bool icL = hasL, icR = hasR;
    if (halo_a != nullptr) {
        if (tid == 0) {
            const unsigned my = xcc_id();
            __hip_atomic_store(xccmap + blk, 0x100u | my, __ATOMIC_RELAXED,
                               __HIP_MEMORY_SCOPE_AGENT);
            unsigned xl = 0, xr = 0;
            if (hasL)
                while (!((xl = __hip_atomic_load(xccmap + blk - NB,
                                                 __ATOMIC_RELAXED,
                                                 __HIP_MEMORY_SCOPE_AGENT)) &
                         0x100u))
                    __builtin_amdgcn_s_sleep(1);
            if (hasR)
                while (!((xr = __hip_atomic_load(xccmap + blk + NB,
                                                 __ATOMIC_RELAXED,
                                                 __HIP_MEMORY_SCOPE_AGENT)) &
                         0x100u))
                    __builtin_amdgcn_s_sleep(1);
            s_ic[0] = (hasL && ((xl & 0xffu) != my)) ? 1u : 0u;
            s_ic[1] = (hasR && ((xr & 0xffu) != my)) ? 1u : 0u;
        }
        __syncthreads();
        icL = s_ic[0] != 0;
        icR = s_ic[1] != 0;
    }

    const long long base = (long long)b * C_ * chanStride;

    // weights w[co][ci=g+4i][k] -> 144 VGPRs, resident (bounds(256,1))
    float wreg[16][K_];
    {
        const float* wb_ = w + (long long)co * C_ * K_;
#pragma unroll
        for (int i = 0; i < 16; ++i)
#pragma unroll
            for (int k = 0; k < K_; ++k)
                wreg[i][k] = wb_[(g + 4 * i) * K_ + k];
    }
    const float bco = bias[co];

    for (int s = 0; s < numSteps; ++s) {
        const int irow = startRow + s * rowDir;
        const long long orowc = base + (long long)co * chanStride +
                                (long long)irow * rowStride;
        const int colL = t0 + g * CPT;

        // RMW input prefetch — independent of neighbors, issue before polls
        float xv[CPT];
        if (colStride == 1) {
            if constexpr (CPT == 4) {
                const float4 v4 = *(const float4*)(buf + orowc + colL);
                xv[0] = v4.x; xv[1] = v4.y; xv[2] = v4.z; xv[3] = v4.w;
            } else {
                const float2 v2 = *(const float2*)(buf + orowc + colL);
                xv[0] = v2.x; xv[1] = v2.y;
            }
        } else {
#pragma unroll
            for (int cc = 0; cc < CPT; ++cc)
                xv[cc] = buf[orowc + (long long)(colL + cc) * colStride];
        }

        if (s == 0) {
            // stage full carry-row window from global (prev direction output)
            const long long pr = base + (long long)(irow - rowDir) * rowStride;
            for (int idx = tid; idx < C_ * WIN; idx += 256) {
                const int ci = idx / WIN, j = idx - ci * WIN;
                const int gc = t0 + j - PAD_;
                float v = 0.f;
                if (gc >= 0 && gc < N)
                    v = buf[pr + (long long)ci * chanStride +
                            (long long)gc * colStride];
                rb[ci * STR + j] = v;
            }
        } else {
            const int par = (s - 1) & 1;
            const unsigned want = (unsigned)s;
            // ---- fast path: wave-local tag poll + one data RMW per lane ---
            {
                const int wv = tid >> 6, lane = tid & 63;
                const int side = wv >> 1;            // waves 0,1: L; 2,3: R
                const bool hasS = side ? hasR : hasL;
                const bool icS = side ? icR : icL;
                if (hasS && !icS) {
                    const int nb = side ? (blk + NB) : (blk - NB);
                    const int nbside = side ^ 1;     // neighbor's far edge
                    const size_t slot = (size_t)((nb * 2 + par) * 2 + nbside);
                    if (lane == 0) {
                        const u64* tp = tags + slot * 8;
                        while ((unsigned)l2_get_u64(tp) != want)
                            __builtin_amdgcn_s_sleep(1);
                    }
                    // wave reconverged: tag seen -> data is at L2
                    const int k = (wv & 1) * 64 + lane;   // 0..127
                    const u64 v = l2_get_u64(halo_p + slot * 128 + k);
                    const int ci = k >> 1, j = k & 1;
                    const int off = side ? (T + 4) : 0;
                    rb[ci * STR + off + j * 2 + 0] =
                        __uint_as_float((unsigned)v);
                    rb[ci * STR + off + j * 2 + 1] =
                        __uint_as_float((unsigned)(v >> 32));
                }
            }
            // ---- cross-XCD fallback: r11 per-thread tag-in-data ----
            if ((hasL && icL) || (hasR && icR)) {
                const int ci = tid >> 2, c = tid & 3;
                if (hasL && icL) {
                    const u64* p = halo_a +
                        (size_t)(((blk - NB) * 2 + par) * 2 + 1) * 256 + tid;
                    u64 v = ic_get_u64(p);
                    while ((unsigned)(v >> 32) != want) {
                        __builtin_amdgcn_s_sleep(1);
                        v = ic_get_u64(p);
                    }
                    rb[ci * STR + c] = __uint_as_float((unsigned)v);
                }
                if (hasR && icR) {
                    const u64* p = halo_a +
                        (size_t)(((blk + NB) * 2 + par) * 2 + 0) * 256 + tid;
                    u64 v = ic_get_u64(p);
                    while ((unsigned)(v >> 32) != want) {
                        __builtin_amdgcn_s_sleep(1);
                        v = ic_get_u64(p);
                    }
                    rb[ci * STR + T + 4 + c] = __uint_as_float((unsigned)v);
                }
            }
        }
        __syncthreads();  // SYNC_A: halos + interior updates visible

        // ---- conv: partial sums over my ci-quarter, all T cols ----
        float acc[T];
#pragma unroll
        for (int c = 0; c < T; ++c) acc[c] = 0.f;
#pragma unroll
        for (int i = 0; i < 16; ++i) {
            const float* rp = rb + (g + 4 * i) * STR;
            float win[WIN];
#pragma unroll
            for (int j = 0; j < WIN / 4; ++j) {
                const float4 v = *(const float4*)(rp + 4 * j);
                win[4 * j + 0] = v.x; win[4 * j + 1] = v.y;
                win[4 * j + 2] = v.z; win[4 * j + 3] = v.w;
            }
#pragma unroll
            for (int k = 0; k < K_; ++k) {
                const float wk = wreg[i][k];
#pragma unroll
                for (int c = 0; c < T; ++c)
                    acc[c] = fmaf(wk, win[c + k], acc[c]);
            }
        }
        // butterfly over g (lane bits 0-1): full sums in all 4 siblings
#pragma unroll
        for (int c = 0; c < T; ++c) acc[c] += __shfl_xor(acc[c], 1);
#pragma unroll
        for (int c = 0; c < T; ++c) acc[c] += __shfl_xor(acc[c], 2);

        float r[CPT];
#pragma unroll
        for (int cc = 0; cc < CPT; ++cc)
            r[cc] = xv[cc] + fmaxf(acc[g * CPT + cc] + bco, 0.f);

        // ---- export edges (atomic pair-swaps fast path / IC tagged) ----
        const int epar = s & 1;
        if (s != numSteps - 1 && halo_a != nullptr) {
            const unsigned tag = (unsigned)(s + 1);
            if constexpr (CPT == 2) {
                const int side = g >> 1;           // g0,g1 left; g2,g3 right
                const bool has = side ? hasR : hasL;
                const bool ic = side ? icR : icL;
                if (has && !ic) {
                    u64* p = halo_p +
                        (size_t)((blk * 2 + epar) * 2 + side) * 128 +
                        co * 2 + (g & 1);
                    l2_put_u64(p, pack2f(r[0], r[1]));
                } else if (has) {
                    u64* p = halo_a +
                        (size_t)((blk * 2 + epar) * 2 + side) * 256 +
                        co * 4 + (g & 1) * 2;
                    ic_put_u64(p, pack_tag(r[0], tag));
                    ic_put_u64(p + 1, pack_tag(r[1], tag));
                }
            } else {  // CPT==4: g0 owns full left edge, g3 full right edge
                if ((g == 0 && hasL) || (g == 3 && hasR)) {
                    const int side = (g == 0) ? 0 : 1;
                    const bool ic = (g == 0) ? icL : icR;
                    if (!ic) {
                        u64* p = halo_p +
                            (size_t)((blk * 2 + epar) * 2 + side) * 128 +
                            co * 2;
                        l2_put_u64(p, pack2f(r[0], r[1]));
                        l2_put_u64(p + 1, pack2f(r[2], r[3]));
                    } else {
                        u64* p = halo_a +
                            (size_t)((blk * 2 + epar) * 2 + side) * 256 +
                            co * 4;
#pragma unroll
                        for (int cc = 0; cc < 4; ++cc)
                            ic_put_u64(p + cc, pack_tag(r[cc], tag));
                    }
                }
            }
        }

        // SYNC_B: all conv reads of rb done AND (compiler-emitted vmcnt(0)
        // before s_barrier) all export atomics committed at the L2.
        __syncthreads();

        // tag publish (fast-path links only; one thread per side)
        if (s != numSteps - 1 && halo_a != nullptr) {
            if (tid == 0 && hasL && !icL)
                l2_put_u64(tags + (size_t)((blk * 2 + epar) * 2 + 0) * 8,
                           (u64)(s + 1));
            if (tid == 64 && hasR && !icR)
                l2_put_u64(tags + (size_t)((blk * 2 + epar) * 2 + 1) * 8,
                           (u64)(s + 1));
        }

        // output row stores (block-private; off the inter-block chain)
        if (colStride == 1) {
            if constexpr (CPT == 4) {
                const float4 v4 = {r[0], r[1], r[2], r[3]};
                *(float4*)(buf + orowc + colL) = v4;
            } else {
                const float2 v2 = {r[0], r[1]};
                *(float2*)(buf + orowc + colL) = v2;
            }
        } else {
#pragma unroll
            for (int cc = 0; cc < CPT; ++cc)
                buf[orowc + (long long)(colL + cc) * colStride] = r[cc];
        }

        // own outputs become next step's carry (interior slots; next import
        // writes halo slots — disjoint, covered by next SYNC_A)
#pragma unroll
        for (int cc = 0; cc < CPT; ++cc)
            rb[co * STR + 4 + g * CPT + cc] = r[cc];
    }
}

// out[b,c,s,r] = in[b,c,r,s] for each of the B*C planes.
__global__ __launch_bounds__(256) void transpose_kernel(
    const float* __restrict__ in, float* __restrict__ out,
    const int R, const int S)
{
    __shared__ float tile[32][33];
    const size_t plane = (size_t)blockIdx.z * R * S;
    const int s0 = blockIdx.x * 32;
    const int r0 = blockIdx.y * 32;
    const int tx = threadIdx.x;
    const int ty = threadIdx.y;
#pragma unroll
    for (int j = 0; j < 32; j += 8)
        tile[ty + j][tx] = in[plane + (size_t)(r0 + ty + j) * S + s0 + tx];
    __syncthreads();
#pragma unroll
    for (int j = 0; j < 32; j += 8)
        out[plane + (size_t)(s0 + ty + j) * R + r0 + tx] = tile[tx][ty + j];
}

template <int T>
static void launch_dir(float* buf, const float* w, const float* bias, int N,
                       long long rowStride, long long colStride,
                       long long chanStride, int startRow, int rowDir,
                       int numSteps, u64* halo_a, u64* halo_p, u64* tags,
                       unsigned* xccmap, bool persistent, hipStream_t stream)
{
    const int nblocks = 8 * (N / T);   // 256 for both variants
    if (persistent) {
        scan_pair_kernel<T><<<nblocks, 256, 0, stream>>>(
            buf, w, bias, N, rowStride, colStride, chanStride, startRow,
            rowDir, numSteps, halo_a, halo_p, tags, xccmap);
    } else {
        for (int s = 0; s < numSteps; ++s)
            scan_pair_kernel<T><<<nblocks, 256, 0, stream>>>(
                buf, w, bias, N, rowStride, colStride, chanStride,
                startRow + s * rowDir, rowDir, 1, nullptr, nullptr, nullptr,
                nullptr);
    }
}

extern "C" void kernel_launch(void* const* d_in, const int* in_sizes, int n_in,
                              void* d_out, int out_size, void* d_ws,
                              size_t ws_size, hipStream_t stream)
{
    const float* x    = (const float*)d_in[0];
    const float* w_ud = (const float*)d_in[1];
    const float* b_ud = (const float*)d_in[2];
    const float* w_du = (const float*)d_in[3];
    const float* b_du = (const float*)d_in[4];
    const float* w_lr = (const float*)d_in[5];
    const float* b_lr = (const float*)d_in[6];
    const float* w_rl = (const float*)d_in[7];
    const float* b_rl = (const float*)d_in[8];
    float* out = (float*)d_out;

    const size_t total = (size_t)B_ * C_ * H_ * W_;
    const long long chan = (long long)H_ * W_;

    const bool haveSync = ws_size >= HALO_P_OFF + 4 * HALO_P_PER_DIR;
    const bool haveT = ws_size >= TBUF_OFF + total * sizeof(float);

    float* wsT = (float*)((char*)d_ws + TBUF_OFF);

    hipMemcpyAsync(out, x, total * sizeof(float), hipMemcpyDeviceToDevice,
                   stream);
    // zero xcc map + tags + IC halos (kills stale tags across graph replays;
    // halo_p needs no reset — its validity is gated by the tags)
    if (haveSync) hipMemsetAsync(d_ws, 0, INIT_BYTES, stream);

    u64* ha[4];
    u64* hp[4];
    u64* tg[4];
    unsigned* xm[4];
    for (int d = 0; d < 4; ++d) {
        ha[d] = (u64*)((char*)d_ws + HALO_A_OFF + d * HALO_A_PER_DIR);
        hp[d] = (u64*)((char*)d_ws + HALO_P_OFF + d * HALO_P_PER_DIR);
        tg[d] = (u64*)((char*)d_ws + TAG_OFF + d * TAG_PER_DIR);
        xm[d] = (unsigned*)((char*)d_ws + XCC_OFF + d * XCC_PER_DIR);
    }

    // up->down / down->up on [b,c,h,w]: scan h, conv along w (contig, N=512)
    launch_dir<16>(out, w_ud, b_ud, W_, (long long)W_, 1LL, chan,
                   1, +1, H_ - 1, ha[0], hp[0], tg[0], xm[0], haveSync,
                   stream);
    launch_dir<16>(out, w_du, b_du, W_, (long long)W_, 1LL, chan,
                   H_ - 2, -1, H_ - 1, ha[1], hp[1], tg[1], xm[1], haveSync,
                   stream);

    if (haveT) {
        // transpose to [b,c,w,h]: scan w, conv along h (contig, N=256)
        {
            dim3 gt(W_ / 32, H_ / 32, B_ * C_);
            transpose_kernel<<<gt, dim3(32, 8), 0, stream>>>(out, wsT, H_, W_);
        }
        launch_dir<8>(wsT, w_lr, b_lr, H_, (long long)H_, 1LL, chan,
                      1, +1, W_ - 1, ha[2], hp[2], tg[2], xm[2], haveSync,
                      stream);
        launch_dir<8>(wsT, w_rl, b_rl, H_, (long long)H_, 1LL, chan,
                      W_ - 2, -1, W_ - 1, ha[3], hp[3], tg[3], xm[3], haveSync,
                      stream);
        {
            dim3 gt(H_ / 32, W_ / 32, B_ * C_);
            transpose_kernel<<<gt, dim3(32, 8), 0, stream>>>(wsT, out, W_, H_);
        }
    } else {
        // strided fallback on [b,c,h,w]: scan w (rowStride=1), conv along h
        launch_dir<8>(out, w_lr, b_lr, H_, 1LL, (long long)W_, chan,
                      1, +1, W_ - 1, ha[2], hp[2], tg[2], xm[2], haveSync,
                      stream);
        launch_dir<8>(out, w_rl, b_rl, H_, 1LL, (long long)W_, chan,
                      W_ - 2, -1, W_ - 1, ha[3], hp[3], tg[3], xm[3], haveSync,
                      stream);
    }
}

// Round 14
// 3112.824 us; speedup vs baseline: 5.4095x; 2.9239x over previous
//
#include <hip/hip_runtime.h>

static constexpr int B_ = 8;
static constexpr int C_ = 64;
static constexpr int H_ = 256;
static constexpr int W_ = 512;
static constexpr int K_ = 9;
static constexpr int PAD_ = 4;

static constexpr int T_ = 16;     // cols per block tile (MFMA N)
static constexpr int WIN_ = 24;   // staged window cols (T + 2*PAD)
static constexpr int CIW_ = 72;   // LDS ci-row width (64 + 8 pad: b128 2-way only)
static constexpr int NB_ = 8;     // chain-neighbor stride in blockIdx

typedef unsigned long long u64;
typedef unsigned int u32;
typedef __attribute__((ext_vector_type(8))) short bf16x8;  // 8 bf16 = 4 VGPR
typedef __attribute__((ext_vector_type(4))) float f32x4;

// workspace layout (bytes) — identical to round 13 (proven protocol)
static constexpr size_t XCC_OFF = 0;
static constexpr size_t XCC_PER_DIR = 256 * 4;
static constexpr size_t TAG_OFF = 64ull << 10;
static constexpr size_t TAG_PER_DIR = 128ull << 10;
static constexpr size_t HALO_A_OFF = 1ull << 20;
static constexpr size_t HALO_A_PER_DIR = 2ull << 20;
static constexpr size_t INIT_BYTES = HALO_A_OFF + 4 * HALO_A_PER_DIR;  // 9 MB
static constexpr size_t HALO_P_OFF = 9ull << 20;
static constexpr size_t HALO_P_PER_DIR = 1ull << 20;
static constexpr size_t TBUF_OFF = 16ull << 20;

// ---------- sync primitives (r13-proven; see r9/r10/r12 failure ledger) ----
__device__ __forceinline__ void l2_put_u64(u64* p, u64 v) {
    asm volatile("global_atomic_swap_x2 %0, %1, off" :: "v"(p), "v"(v)
                 : "memory");
}
__device__ __forceinline__ u64 l2_get_u64(const u64* p) {
    u64 v;
    asm volatile("global_atomic_add_x2 %0, %1, %2, off sc0\n\t"
                 "s_waitcnt vmcnt(0)"
                 : "=&v"(v) : "v"(p), "v"(0ull) : "memory");
    return v;
}
__device__ __forceinline__ u64 ic_get_u64(const u64* p) {
    return __hip_atomic_load(p, __ATOMIC_RELAXED, __HIP_MEMORY_SCOPE_AGENT);
}
__device__ __forceinline__ void ic_put_u64(u64* p, u64 v) {
    (void)__hip_atomic_exchange(p, v, __ATOMIC_RELAXED,
                                __HIP_MEMORY_SCOPE_AGENT);
}
__device__ __forceinline__ u64 pack_tag(float val, unsigned tag) {
    return (u64)__float_as_uint(val) | ((u64)tag << 32);
}
__device__ __forceinline__ u64 pack2f(float a, float b) {
    return (u64)__float_as_uint(a) | ((u64)__float_as_uint(b) << 32);
}
__device__ __forceinline__ unsigned xcc_id() {
    unsigned v;
    asm volatile("s_getreg_b32 %0, hwreg(HW_REG_XCC_ID)" : "=s"(v));
    return v & 0xffu;
}
// fp32 -> bf16 round-to-nearest-even (bit trick, no header dependency)
__device__ __forceinline__ unsigned short f2bf(float f) {
    const u32 u = __float_as_uint(f);
    return (unsigned short)((u + 0x7fffu + ((u >> 16) & 1u)) >> 16);
}

// Persistent directional scan with bf16-MFMA conv engine.
// Per block/step: P[64co][16col] = W[64co][576] x im2col(carry row)[576][16]
// via 18 x mfma_f32_16x16x32_bf16. k-order = tap*64+ci: chunk t has
// tap=t>>1, ci=(t&1)*32 + 0..31. Carry row in LDS TRANSPOSED bf16
// prevT[col][ci] -> B-frag (lane: n=l&15, q=l>>4, elem j) =
// prevT[n+tap][(t&1)*32+q*8+j] = one aligned ds_read_b128. A-frag: W row
// co=16*wave+n, same k-slice -> 18 short8 regs (one-time). A and B share
// the per-lane k-map, so any HW k-permutation cancels. D (verified m89):
// col=lane&15, row=(lane>>4)*4+reg -> lane owns (co0..co0+3, col n),
// co0=16*wave+4*q. Carry state fp32 in global; bf16 only at MFMA inputs
// (f2bf applied identically on both halo and interior paths).
// Sync protocol = r13 verbatim (pair-packed L2 atomics + central tags;
// IC tag-in-data fallback for cross-XCD links; parity-2 slots).
__global__ __launch_bounds__(256, 1) void scan_mfma_kernel(
    float* __restrict__ buf, const float* __restrict__ w,
    const float* __restrict__ bias, const int N,
    const long long rowStride, const long long colStride,
    const long long chanStride, const int startRow, const int rowDir,
    const int numSteps, u64* __restrict__ halo_a, u64* __restrict__ halo_p,
    u64* __restrict__ tags, unsigned* __restrict__ xccmap)
{
    __shared__ __attribute__((aligned(16))) unsigned short prevT[WIN_][CIW_];
    __shared__ unsigned s_ic[2];

    const int tid = threadIdx.x;
    const int wv = tid >> 6;
    const int lane = tid & 63;
    const int n = lane & 15;   // B n-axis = D col = col-in-tile
    const int q = lane >> 4;   // k-group; D row group
    const int blk = blockIdx.x;
    const int b = blk & 7;
    const int tile = blk >> 3;
    const int TPB = N / T_;
    const int t0 = tile * T_;
    const bool hasL = tile > 0;
    const bool hasR = tile < TPB - 1;

    // ---- one-time link-scope discovery (r13 verbatim) ----
    bool icL = hasL, icR = hasR;
    if (halo_a != nullptr) {
        if (tid == 0) {
            const unsigned my = xcc_id();
            __hip_atomic_store(xccmap + blk, 0x100u | my, __ATOMIC_RELAXED,
                               __HIP_MEMORY_SCOPE_AGENT);
            unsigned xl = 0, xr = 0;
            if (hasL)
                while (!((xl = __hip_atomic_load(xccmap + blk - NB_,
                                                 __ATOMIC_RELAXED,
                                                 __HIP_MEMORY_SCOPE_AGENT)) &
                         0x100u))
                    __builtin_amdgcn_s_sleep(1);
            if (hasR)
                while (!((xr = __hip_atomic_load(xccmap + blk + NB_,
                                                 __ATOMIC_RELAXED,
                                                 __HIP_MEMORY_SCOPE_AGENT)) &
                         0x100u))
                    __builtin_amdgcn_s_sleep(1);
            s_ic[0] = (hasL && ((xl & 0xffu) != my)) ? 1u : 0u;
            s_ic[1] = (hasR && ((xr & 0xffu) != my)) ? 1u : 0u;
        }
        __syncthreads();
        icL = s_ic[0] != 0;
        icR = s_ic[1] != 0;
    }

    const long long base = (long long)b * C_ * chanStride;

    // ---- one-time: A-fragments (weights, bf16) -> 18 x short8 regs ----
    bf16x8 af[18];
    {
        const float* wr = w + (long long)(wv * 16 + n) * (C_ * K_);
#pragma unroll
        for (int t = 0; t < 18; ++t) {
            const int tap = t >> 1;
            const int ci0 = (t & 1) * 32 + q * 8;
            bf16x8 a;
#pragma unroll
            for (int j = 0; j < 8; ++j)
                a[j] = (short)f2bf(wr[(ci0 + j) * K_ + tap]);
            af[t] = a;
        }
    }
    const int co0 = wv * 16 + q * 4;  // this lane's 4 output channels
    float bv[4];
#pragma unroll
    for (int i = 0; i < 4; ++i) bv[i] = bias[co0 + i];

    for (int s = 0; s < numSteps; ++s) {
        const int irow = startRow + s * rowDir;
        const long long orow = base + (long long)irow * rowStride;
        const int col = t0 + n;

        // RMW input prefetch (4 co x 1 col) — issue before polls
        float xv[4];
#pragma unroll
        for (int i = 0; i < 4; ++i)
            xv[i] = buf[orow + (long long)(co0 + i) * chanStride +
                        (long long)col * colStride];

        if (s == 0) {
            // stage carry row window, transposed bf16 (zeros OOB; edge-tile
            // halo cols stay zero forever — only imports overwrite them)
            const long long pr = base + (long long)(irow - rowDir) * rowStride;
            for (int idx = tid; idx < WIN_ * C_; idx += 256) {
                const int c = idx >> 6, ci = idx & 63;
                const int gc = t0 + c - PAD_;
                float v = 0.f;
                if (gc >= 0 && gc < N)
                    v = buf[pr + (long long)ci * chanStride +
                            (long long)gc * colStride];
                prevT[c][ci] = f2bf(v);
            }
        } else {
            const int par = (s - 1) & 1;
            const unsigned want = (unsigned)s;
            // fast path: waves 0,1 left / 2,3 right; lane0 polls central tag
            {
                const int side = wv >> 1;
                const bool hasS = side ? hasR : hasL;
                const bool icS = side ? icR : icL;
                if (hasS && !icS) {
                    const int nb = side ? (blk + NB_) : (blk - NB_);
                    const size_t slot =
                        (size_t)((nb * 2 + par) * 2 + (side ^ 1));
                    if (lane == 0) {
                        const u64* tp = tags + slot * 8;
                        while ((unsigned)l2_get_u64(tp) != want)
                            __builtin_amdgcn_s_sleep(1);
                    }
                    // wave reconverged: data pairs are at the L2
                    const int k = (wv & 1) * 64 + lane;  // 0..127
                    const u64 v = l2_get_u64(halo_p + slot * 128 + k);
                    const int hc = k >> 5;               // halo col 0..3
                    const int cp = k & 31;               // co pair
                    const int off = side ? (T_ + 4) : 0;
                    prevT[off + hc][2 * cp + 0] =
                        f2bf(__uint_as_float((u32)v));
                    prevT[off + hc][2 * cp + 1] =
                        f2bf(__uint_as_float((u32)(v >> 32)));
                }
            }
            // cross-XCD fallback: per-thread tag-in-data agent atomics
            if ((hasL && icL) || (hasR && icR)) {
                if (hasL && icL) {
                    const u64* p = halo_a +
                        (size_t)(((blk - NB_) * 2 + par) * 2 + 1) * 256 + tid;
                    u64 v = ic_get_u64(p);
                    while ((unsigned)(v >> 32) != want) {
                        __builtin_amdgcn_s_sleep(1);
                        v = ic_get_u64(p);
                    }
                    prevT[tid >> 6][tid & 63] =
                        f2bf(__uint_as_float((u32)v));
                }
                if (hasR && icR) {
                    const u64* p = halo_a +
                        (size_t)(((blk + NB_) * 2 + par) * 2 + 0) * 256 + tid;
                    u64 v = ic_get_u64(p);
                    while ((unsigned)(v >> 32) != want) {
                        __builtin_amdgcn_s_sleep(1);
                        v = ic_get_u64(p);
                    }
                    prevT[T_ + 4 + (tid >> 6)][tid & 63] =
                        f2bf(__uint_as_float((u32)v));
                }
            }
        }
        __syncthreads();  // SYNC_A: halo + interior carry visible to all

        // ---- conv via 18 x MFMA 16x16x32 bf16 ----
        f32x4 acc = {0.f, 0.f, 0.f, 0.f};
#pragma unroll
        for (int t = 0; t < 18; ++t) {
            const int tap = t >> 1;
            const int ci0 = (t & 1) * 32 + q * 8;
            const bf16x8 bf = *(const bf16x8*)&prevT[n + tap][ci0];
            acc = __builtin_amdgcn_mfma_f32_16x16x32_bf16(af[t], bf, acc,
                                                          0, 0, 0);
        }

        float r[4];
#pragma unroll
        for (int i = 0; i < 4; ++i)
            r[i] = xv[i] + fmaxf(acc[i] + bv[i], 0.f);

        // ---- export edge cols (r13 protocol, lane-remapped payload) ----
        const int epar = s & 1;
        if (s != numSteps - 1 && halo_a != nullptr) {
            const unsigned tag = (unsigned)(s + 1);
            const bool isL = (n < 4) && hasL;
            const bool isR = (n >= T_ - 4) && hasR;
            if (isL || isR) {
                const int side = isR ? 1 : 0;
                const int hc = isR ? (n - (T_ - 4)) : n;
                const bool ic = isR ? icR : icL;
                if (!ic) {
                    u64* p = halo_p +
                        (size_t)((blk * 2 + epar) * 2 + side) * 128 +
                        hc * 32 + (co0 >> 1);
                    l2_put_u64(p, pack2f(r[0], r[1]));
                    l2_put_u64(p + 1, pack2f(r[2], r[3]));
                } else {
                    u64* p = halo_a +
                        (size_t)((blk * 2 + epar) * 2 + side) * 256 +
                        hc * 64 + co0;
#pragma unroll
                    for (int i = 0; i < 4; ++i)
                        ic_put_u64(p + i, pack_tag(r[i], tag));
                }
            }
        }

        // SYNC_B: all B-frag reads done AND export atomics drained to L2
        // (compiler emits s_waitcnt vmcnt(0) before s_barrier).
        __syncthreads();

        // central tag publish (one thread per fast-path side)
        if (s != numSteps - 1 && halo_a != nullptr) {
            if (tid == 0 && hasL && !icL)
                l2_put_u64(tags + (size_t)((blk * 2 + epar) * 2 + 0) * 8,
                           (u64)(s + 1));
            if (tid == 64 && hasR && !icR)
                l2_put_u64(tags + (size_t)((blk * 2 + epar) * 2 + 1) * 8,
                           (u64)(s + 1));
        }

        // output row stores (block-private; off the inter-block chain)
#pragma unroll
        for (int i = 0; i < 4; ++i)
            buf[orow + (long long)(co0 + i) * chanStride +
                (long long)col * colStride] = r[i];

        // own outputs -> next step's carry (interior cols; bf16, 4 per lane)
        const u64 pk = (u64)f2bf(r[0]) | ((u64)f2bf(r[1]) << 16) |
                       ((u64)f2bf(r[2]) << 32) | ((u64)f2bf(r[3]) << 48);
        *(u64*)&prevT[4 + n][co0] = pk;
    }
}

// out[b,c,s,r] = in[b,c,r,s] for each of the B*C planes.
__global__ __launch_bounds__(256) void transpose_kernel(
    const float* __restrict__ in, float* __restrict__ out,
    const int R, const int S)
{
    __shared__ float tile[32][33];
    const size_t plane = (size_t)blockIdx.z * R * S;
    const int s0 = blockIdx.x * 32;
    const int r0 = blockIdx.y * 32;
    const int tx = threadIdx.x;
    const int ty = threadIdx.y;
#pragma unroll
    for (int j = 0; j < 32; j += 8)
        tile[ty + j][tx] = in[plane + (size_t)(r0 + ty + j) * S + s0 + tx];
    __syncthreads();
#pragma unroll
    for (int j = 0; j < 32; j += 8)
        out[plane + (size_t)(s0 + ty + j) * R + r0 + tx] = tile[tx][ty + j];
}

static void launch_dir(float* buf, const float* w, const float* bias, int N,
                       long long rowStride, long long colStride,
                       long long chanStride, int startRow, int rowDir,
                       int numSteps, u64* halo_a, u64* halo_p, u64* tags,
                       unsigned* xccmap, bool persistent, hipStream_t stream)
{
    const int nblocks = 8 * (N / T_);   // 256 (N=512) or 128 (N=256)
    if (persistent) {
        scan_mfma_kernel<<<nblocks, 256, 0, stream>>>(
            buf, w, bias, N, rowStride, colStride, chanStride, startRow,
            rowDir, numSteps, halo_a, halo_p, tags, xccmap);
    } else {
        for (int s = 0; s < numSteps; ++s)
            scan_mfma_kernel<<<nblocks, 256, 0, stream>>>(
                buf, w, bias, N, rowStride, colStride, chanStride,
                startRow + s * rowDir, rowDir, 1, nullptr, nullptr, nullptr,
                nullptr);
    }
}

extern "C" void kernel_launch(void* const* d_in, const int* in_sizes, int n_in,
                              void* d_out, int out_size, void* d_ws,
                              size_t ws_size, hipStream_t stream)
{
    const float* x    = (const float*)d_in[0];
    const float* w_ud = (const float*)d_in[1];
    const float* b_ud = (const float*)d_in[2];
    const float* w_du = (const float*)d_in[3];
    const float* b_du = (const float*)d_in[4];
    const float* w_lr = (const float*)d_in[5];
    const float* b_lr = (const float*)d_in[6];
    const float* w_rl = (const float*)d_in[7];
    const float* b_rl = (const float*)d_in[8];
    float* out = (float*)d_out;

    const size_t total = (size_t)B_ * C_ * H_ * W_;
    const long long chan = (long long)H_ * W_;

    const bool haveSync = ws_size >= HALO_P_OFF + 4 * HALO_P_PER_DIR;
    const bool haveT = ws_size >= TBUF_OFF + total * sizeof(float);

    float* wsT = (float*)((char*)d_ws + TBUF_OFF);

    hipMemcpyAsync(out, x, total * sizeof(float), hipMemcpyDeviceToDevice,
                   stream);
    if (haveSync) hipMemsetAsync(d_ws, 0, INIT_BYTES, stream);

    u64* ha[4];
    u64* hp[4];
    u64* tg[4];
    unsigned* xm[4];
    for (int d = 0; d < 4; ++d) {
        ha[d] = (u64*)((char*)d_ws + HALO_A_OFF + d * HALO_A_PER_DIR);
        hp[d] = (u64*)((char*)d_ws + HALO_P_OFF + d * HALO_P_PER_DIR);
        tg[d] = (u64*)((char*)d_ws + TAG_OFF + d * TAG_PER_DIR);
        xm[d] = (unsigned*)((char*)d_ws + XCC_OFF + d * XCC_PER_DIR);
    }

    // up->down / down->up on [b,c,h,w]: scan h, conv along w (contig, N=512)
    launch_dir(out, w_ud, b_ud, W_, (long long)W_, 1LL, chan,
               1, +1, H_ - 1, ha[0], hp[0], tg[0], xm[0], haveSync, stream);
    launch_dir(out, w_du, b_du, W_, (long long)W_, 1LL, chan,
               H_ - 2, -1, H_ - 1, ha[1], hp[1], tg[1], xm[1], haveSync,
               stream);

    if (haveT) {
        // transpose to [b,c,w,h]: scan w, conv along h (contig, N=256)
        {
            dim3 gt(W_ / 32, H_ / 32, B_ * C_);
            transpose_kernel<<<gt, dim3(32, 8), 0, stream>>>(out, wsT, H_, W_);
        }
        launch_dir(wsT, w_lr, b_lr, H_, (long long)H_, 1LL, chan,
                   1, +1, W_ - 1, ha[2], hp[2], tg[2], xm[2], haveSync,
                   stream);
        launch_dir(wsT, w_rl, b_rl, H_, (long long)H_, 1LL, chan,
                   W_ - 2, -1, W_ - 1, ha[3], hp[3], tg[3], xm[3], haveSync,
                   stream);
        {
            dim3 gt(H_ / 32, W_ / 32, B_ * C_);
            transpose_kernel<<<gt, dim3(32, 8), 0, stream>>>(wsT, out, W_, H_);
        }
    } else {
        // strided fallback on [b,c,h,w]: scan w (rowStride=1), conv along h
        launch_dir(out, w_lr, b_lr, H_, 1LL, (long long)W_, chan,
                   1, +1, W_ - 1, ha[2], hp[2], tg[2], xm[2], haveSync,
                   stream);
        launch_dir(out, w_rl, b_rl, H_, 1LL, (long long)W_, chan,
                   W_ - 2, -1, W_ - 1, ha[3], hp[3], tg[3], xm[3], haveSync,
                   stream);
    }
}